// Round 4
// baseline (199.964 us; speedup 1.0000x reference)
//
#include <hip/hip_runtime.h>
#include <hip/hip_bf16.h>
#include <stdint.h>

// BasicBlock: binarized ShuffleNet-style block via XNOR-popcount conv.
// conv = 128*nv - 2*popcount(bits_in ^ bits_w) over valid taps (exact integers).
// fp32 op order replicated with __f*_rn to match reference binarization decisions.
// OUTPUT IS FP32 (reference computes fp32; harness spec: non-bf16 -> float*).

#define HH 56
#define WW 56
#define HW 3136
#define TH 4            // tile rows per block
#define TILES 14        // 56/TH
#define NBATCH 32

// ws layout (bytes)
#define WS_W1B   0u         // 128*9 uint4 = 18432
#define WS_W2B   18432u     // 18432
#define WS_BN    36864u     // floats inv1[128] c1[128] inv2[128] c2[128] = 2048
#define WS_BITS2 40960u     // uint4 per pixel: 32*3136*16 = 1605632
#define WS_RES1  1646592u   // bf16: 32*64*3136*2 = 12845056  (end ~14.5MB)

#define PC(a,b) (__popc((a).x ^ (b).x) + __popc((a).y ^ (b).y) + \
                 __popc((a).z ^ (b).z) + __popc((a).w ^ (b).w))

__global__ __launch_bounds__(256) void prep_kernel(
    const float* __restrict__ w1, const float* __restrict__ w2,
    const float* __restrict__ g1, const float* __restrict__ b1,
    const float* __restrict__ m1, const float* __restrict__ v1,
    const float* __restrict__ g2, const float* __restrict__ b2,
    const float* __restrict__ m2, const float* __restrict__ v2,
    uint4* __restrict__ w1b, uint4* __restrict__ w2b, float* __restrict__ bnc)
{
    int t = blockIdx.x * 256 + threadIdx.x;
    if (t < 2304) {
        const float* w = (t < 1152) ? w1 : w2;
        uint4* dst = (t < 1152) ? w1b : w2b;
        int tt = (t < 1152) ? t : t - 1152;
        int o = tt / 9, tap = tt % 9;
        const float* wp = w + (size_t)o * 1152 + tap;
        uint32_t b[4];
        #pragma unroll
        for (int wd = 0; wd < 4; ++wd) {
            uint32_t acc = 0;
            #pragma unroll
            for (int bi = 0; bi < 32; ++bi) {
                float wv = wp[(size_t)(wd * 32 + bi) * 9];
                acc |= (wv >= 0.0f ? 1u : 0u) << bi;
            }
            b[wd] = acc;
        }
        dst[o * 9 + tap] = make_uint4(b[0], b[1], b[2], b[3]);
    } else if (t < 2432) {
        int c = t - 2304;
        float i1 = __fdiv_rn(g1[c], __fsqrt_rn(__fadd_rn(v1[c], 1e-5f)));
        bnc[c]       = i1;
        bnc[128 + c] = __fsub_rn(b1[c], __fmul_rn(m1[c], i1));
        float i2 = __fdiv_rn(g2[c], __fsqrt_rn(__fadd_rn(v2[c], 1e-5f)));
        bnc[256 + c] = i2;
        bnc[384 + c] = __fsub_rn(b2[c], __fmul_rn(m2[c], i2));
    }
}

// Stage 1: conv1 + bn1 + residual + hardtanh; emits:
//  - bits2: packed binarize(x_act2) (shuffled interleave of out1[0..63] and idle[0..63])
//  - res1 : bf16 out1[0..63] (stage-2 residual, even sub-channels)
//  - out  : odd output planes (final[4m+1] = out1[64+m]+move1[2m],
//           final[4m+3] = x[192+m]+move0[64+m]+move1[2m+1])
__global__ __launch_bounds__(256) void stage1_kernel(
    const float* __restrict__ x, const uint4* __restrict__ w1b,
    const float* __restrict__ bnc, const float* __restrict__ move0,
    const float* __restrict__ move1,
    uint4* __restrict__ bits2, __hip_bfloat16* __restrict__ res1,
    float* __restrict__ out)
{
    const int blk = blockIdx.x;
    const int tile = blk % TILES;
    const int n = blk / TILES;
    const int h0 = tile * TH;
    const int tid = threadIdx.x;

    __shared__ uint32_t sb[(TH + 2) * 60 * 4];   // row stride 60 uint4

    const float* xn = x + (size_t)n * 256 * HW;

    // Phase A: binarize x_act (ch 0..127) for tile+halo into LDS
    for (int hp = tid; hp < (TH + 2) * 58; hp += 256) {
        int hr = hp / 58, hc = hp % 58;
        int gh = h0 - 1 + hr, gw = hc - 1;
        uint32_t wds[4] = {0, 0, 0, 0};
        if (gh >= 0 && gh < HH && gw >= 0 && gw < WW) {
            const float* xp = xn + gh * WW + gw;
            #pragma unroll
            for (int wd = 0; wd < 4; ++wd) {
                uint32_t acc = 0;
                #pragma unroll
                for (int bi = 0; bi < 32; ++bi) {
                    float v = xp[(size_t)(wd * 32 + bi) * HW];
                    acc |= (v >= 0.0f ? 1u : 0u) << bi;
                }
                wds[wd] = acc;
            }
        }
        int l = (hr * 60 + hc) * 4;
        sb[l] = wds[0]; sb[l + 1] = wds[1]; sb[l + 2] = wds[2]; sb[l + 3] = wds[3];
    }
    __syncthreads();

    const int px = tid;
    if (px < TH * WW) {
        const int r = px / WW, cl = px % WW;
        const int gh = h0 + r;
        const uint4* sb4 = (const uint4*)sb;
        // tap validity (zero padding): row/col masks
        const int rok0 = (gh >= 1), rok2 = (gh <= HH - 2);
        const int cok0 = (cl >= 1), cok2 = (cl <= WW - 2);
        const uint32_t rs0 = rok0 ? ~0u : 0u, rs2 = rok2 ? ~0u : 0u;
        const uint32_t csL = cok0 ? ~0u : 0u, csR = cok2 ? ~0u : 0u;
        const int nvbase = ((1 + rok0 + rok2) * (1 + cok0 + cok2)) << 7;
        // hoist 3x3 window of packed input bits (invariant over out-channels)
        const uint4 i00 = sb4[(r + 0) * 60 + cl + 0];
        const uint4 i01 = sb4[(r + 0) * 60 + cl + 1];
        const uint4 i02 = sb4[(r + 0) * 60 + cl + 2];
        const uint4 i10 = sb4[(r + 1) * 60 + cl + 0];
        const uint4 i11 = sb4[(r + 1) * 60 + cl + 1];
        const uint4 i12 = sb4[(r + 1) * 60 + cl + 2];
        const uint4 i20 = sb4[(r + 2) * 60 + cl + 0];
        const uint4 i21 = sb4[(r + 2) * 60 + cl + 1];
        const uint4 i22 = sb4[(r + 2) * 60 + cl + 2];

        const int poff = gh * WW + cl;
        uint32_t bw0 = 0, bw1 = 0, bw2 = 0, bw3 = 0;

        for (int j = 0; j < 128; ++j) {
            uint4 wt[9];
            #pragma unroll
            for (int tp = 0; tp < 9; ++tp) wt[tp] = w1b[j * 9 + tp];
            int acc = 0;
            acc += PC(wt[0], i00) & (int)(rs0 & csL);
            acc += PC(wt[1], i01) & (int)rs0;
            acc += PC(wt[2], i02) & (int)(rs0 & csR);
            acc += PC(wt[3], i10) & (int)csL;
            acc += PC(wt[4], i11);
            acc += PC(wt[5], i12) & (int)csR;
            acc += PC(wt[6], i20) & (int)(rs2 & csL);
            acc += PC(wt[7], i21) & (int)rs2;
            acc += PC(wt[8], i22) & (int)(rs2 & csR);
            float convf = (float)(nvbase - (acc << 1));
            float bno = __fadd_rn(__fmul_rn(convf, bnc[j]), bnc[128 + j]);
            float resv = xn[(size_t)j * HW + poff];
            float v2 = __fadd_rn(bno, resv);
            float vc = fminf(fmaxf(v2, -1.0f), 1.0f);
            if (j < 64) {
                // shuffled ch2 = 2j -> bits2 word j>>4, bit 2*(j&15)
                uint32_t m = (v2 >= 0.0f ? 1u : 0u) << (2 * (j & 15));
                int wd = j >> 4;
                if (wd == 0) bw0 |= m; else if (wd == 1) bw1 |= m;
                else if (wd == 2) bw2 |= m; else bw3 |= m;
                res1[(size_t)(n * 64 + j) * HW + poff] = __float2bfloat16(vc);
            } else {
                // final[2i+1], i = 2*(j-64): plane 4*(j-64)+1
                int i2 = 2 * (j - 64);
                out[(size_t)(n * 256 + 2 * i2 + 1) * HW + poff] =
                    __fadd_rn(vc, move1[i2]);
            }
        }
        // idle bits: shuffled ch2 = 2k+1 from sign(x[128+k] + move0[k])
        for (int k2 = 0; k2 < 64; ++k2) {
            float v = xn[(size_t)(128 + k2) * HW + poff];
            float s = __fadd_rn(v, move0[k2]);
            uint32_t m = (s >= 0.0f ? 1u : 0u) << (2 * (k2 & 15) + 1);
            int wd = k2 >> 4;
            if (wd == 0) bw0 |= m; else if (wd == 1) bw1 |= m;
            else if (wd == 2) bw2 |= m; else bw3 |= m;
        }
        bits2[(size_t)n * HW + poff] = make_uint4(bw0, bw1, bw2, bw3);
    }

    // pass-through planes 4m+3 = x[192+m] + move0[64+m] + move1[2m+1]
    for (int idx = tid; idx < 64 * TH * WW; idx += 256) {
        int m = idx / (TH * WW);
        int p = idx % (TH * WW);
        int lh = p / WW, lw = p % WW;
        int poff = (h0 + lh) * WW + lw;
        float xv = xn[(size_t)(192 + m) * HW + poff];
        float val = __fadd_rn(__fadd_rn(xv, move0[64 + m]), move1[2 * m + 1]);
        out[(size_t)(n * 256 + 4 * m + 3) * HW + poff] = val;
    }
}

// Stage 2: conv2 + bn2 + residual + hardtanh -> even output planes (plane 2j)
__global__ __launch_bounds__(256) void stage2_kernel(
    const float* __restrict__ x, const uint4* __restrict__ w2b,
    const float* __restrict__ bnc, const float* __restrict__ move0,
    const uint4* __restrict__ bits2, const __hip_bfloat16* __restrict__ res1,
    float* __restrict__ out)
{
    const int blk = blockIdx.x;
    const int tile = blk % TILES;
    const int n = blk / TILES;
    const int h0 = tile * TH;
    const int tid = threadIdx.x;

    __shared__ uint32_t sb[(TH + 2) * 60 * 4];

    const uint4* bsrc = bits2 + (size_t)n * HW;
    for (int hp = tid; hp < (TH + 2) * 58; hp += 256) {
        int hr = hp / 58, hc = hp % 58;
        int gh = h0 - 1 + hr, gw = hc - 1;
        uint4 v = make_uint4(0, 0, 0, 0);
        if (gh >= 0 && gh < HH && gw >= 0 && gw < WW) v = bsrc[gh * WW + gw];
        int l = (hr * 60 + hc) * 4;
        sb[l] = v.x; sb[l + 1] = v.y; sb[l + 2] = v.z; sb[l + 3] = v.w;
    }
    __syncthreads();

    const int px = tid;
    if (px >= TH * WW) return;
    const int r = px / WW, cl = px % WW;
    const int gh = h0 + r;
    const uint4* sb4 = (const uint4*)sb;
    const int rok0 = (gh >= 1), rok2 = (gh <= HH - 2);
    const int cok0 = (cl >= 1), cok2 = (cl <= WW - 2);
    const uint32_t rs0 = rok0 ? ~0u : 0u, rs2 = rok2 ? ~0u : 0u;
    const uint32_t csL = cok0 ? ~0u : 0u, csR = cok2 ? ~0u : 0u;
    const int nvbase = ((1 + rok0 + rok2) * (1 + cok0 + cok2)) << 7;
    const uint4 i00 = sb4[(r + 0) * 60 + cl + 0];
    const uint4 i01 = sb4[(r + 0) * 60 + cl + 1];
    const uint4 i02 = sb4[(r + 0) * 60 + cl + 2];
    const uint4 i10 = sb4[(r + 1) * 60 + cl + 0];
    const uint4 i11 = sb4[(r + 1) * 60 + cl + 1];
    const uint4 i12 = sb4[(r + 1) * 60 + cl + 2];
    const uint4 i20 = sb4[(r + 2) * 60 + cl + 0];
    const uint4 i21 = sb4[(r + 2) * 60 + cl + 1];
    const uint4 i22 = sb4[(r + 2) * 60 + cl + 2];

    const float* xn = x + (size_t)n * 256 * HW;
    const int poff = gh * WW + cl;

    for (int j = 0; j < 128; ++j) {
        uint4 wt[9];
        #pragma unroll
        for (int tp = 0; tp < 9; ++tp) wt[tp] = w2b[j * 9 + tp];
        int acc = 0;
        acc += PC(wt[0], i00) & (int)(rs0 & csL);
        acc += PC(wt[1], i01) & (int)rs0;
        acc += PC(wt[2], i02) & (int)(rs0 & csR);
        acc += PC(wt[3], i10) & (int)csL;
        acc += PC(wt[4], i11);
        acc += PC(wt[5], i12) & (int)csR;
        acc += PC(wt[6], i20) & (int)(rs2 & csL);
        acc += PC(wt[7], i21) & (int)rs2;
        acc += PC(wt[8], i22) & (int)(rs2 & csR);
        float convf = (float)(nvbase - (acc << 1));
        float bno = __fadd_rn(__fmul_rn(convf, bnc[256 + j]), bnc[384 + j]);
        float resv;
        if (j & 1) {
            resv = __fadd_rn(xn[(size_t)(128 + (j >> 1)) * HW + poff], move0[j >> 1]);
        } else {
            resv = __bfloat162float(res1[(size_t)(n * 64 + (j >> 1)) * HW + poff]);
        }
        float v2 = __fadd_rn(bno, resv);
        float vc = fminf(fmaxf(v2, -1.0f), 1.0f);
        out[(size_t)(n * 256 + 2 * j) * HW + poff] = vc;
    }
}

extern "C" void kernel_launch(void* const* d_in, const int* in_sizes, int n_in,
                              void* d_out, int out_size, void* d_ws, size_t ws_size,
                              hipStream_t stream)
{
    const float* x   = (const float*)d_in[0];
    const float* w1  = (const float*)d_in[1];
    const float* w2  = (const float*)d_in[2];
    const float* g1  = (const float*)d_in[3];
    const float* b1  = (const float*)d_in[4];
    const float* m1  = (const float*)d_in[5];
    const float* v1  = (const float*)d_in[6];
    const float* g2  = (const float*)d_in[7];
    const float* b2  = (const float*)d_in[8];
    const float* m2  = (const float*)d_in[9];
    const float* v2  = (const float*)d_in[10];
    const float* mv0 = (const float*)d_in[11];
    const float* mv1 = (const float*)d_in[12];

    uint8_t* ws = (uint8_t*)d_ws;
    uint4* w1b = (uint4*)(ws + WS_W1B);
    uint4* w2b = (uint4*)(ws + WS_W2B);
    float* bnc = (float*)(ws + WS_BN);
    uint4* bits2 = (uint4*)(ws + WS_BITS2);
    __hip_bfloat16* res1 = (__hip_bfloat16*)(ws + WS_RES1);
    float* outp = (float*)d_out;

    hipLaunchKernelGGL(prep_kernel, dim3(10), dim3(256), 0, stream,
                       w1, w2, g1, b1, m1, v1, g2, b2, m2, v2, w1b, w2b, bnc);
    hipLaunchKernelGGL(stage1_kernel, dim3(TILES * NBATCH), dim3(256), 0, stream,
                       x, w1b, bnc, mv0, mv1, bits2, res1, outp);
    hipLaunchKernelGGL(stage2_kernel, dim3(TILES * NBATCH), dim3(256), 0, stream,
                       x, w2b, bnc, mv0, bits2, res1, outp);
}

// Round 5
// 163.396 us; speedup vs baseline: 1.2238x; 1.2238x over previous
//
#include <hip/hip_runtime.h>
#include <hip/hip_bf16.h>
#include <stdint.h>

// BasicBlock: binarized ShuffleNet-style block via XNOR-popcount conv.
// conv = 128*nv - 2*popcount(bits_in ^ bits_w) over valid taps (exact integers).
// fp32 op order replicated with __f*_rn to match reference binarization decisions.
// R5: 512-thread blocks (j-split across wave groups) + weights staged in LDS.

#define HH 56
#define WW 56
#define HW 3136
#define TH 4            // tile rows per block
#define TILES 14        // 56/TH
#define NBATCH 32

// ws layout (bytes)
#define WS_W1B   0u         // 128*9 uint4 = 18432
#define WS_W2B   18432u     // 18432
#define WS_BN    36864u     // floats inv1[128] c1[128] inv2[128] c2[128] = 2048
#define WS_BITS2 40960u     // uint4 per pixel: 32*3136*16 = 1605632
#define WS_RES1  1646592u   // bf16: 32*64*3136*2 = 12845056  (end ~14.5MB)

#define PC(a,b) (__popc((a).x ^ (b).x) + __popc((a).y ^ (b).y) + \
                 __popc((a).z ^ (b).z) + __popc((a).w ^ (b).w))

__global__ __launch_bounds__(256) void prep_kernel(
    const float* __restrict__ w1, const float* __restrict__ w2,
    const float* __restrict__ g1, const float* __restrict__ b1,
    const float* __restrict__ m1, const float* __restrict__ v1,
    const float* __restrict__ g2, const float* __restrict__ b2,
    const float* __restrict__ m2, const float* __restrict__ v2,
    uint4* __restrict__ w1b, uint4* __restrict__ w2b, float* __restrict__ bnc)
{
    int t = blockIdx.x * 256 + threadIdx.x;
    if (t < 2304) {
        const float* w = (t < 1152) ? w1 : w2;
        uint4* dst = (t < 1152) ? w1b : w2b;
        int tt = (t < 1152) ? t : t - 1152;
        int o = tt / 9, tap = tt % 9;
        const float* wp = w + (size_t)o * 1152 + tap;
        uint32_t b[4];
        #pragma unroll
        for (int wd = 0; wd < 4; ++wd) {
            uint32_t acc = 0;
            #pragma unroll
            for (int bi = 0; bi < 32; ++bi) {
                float wv = wp[(size_t)(wd * 32 + bi) * 9];
                acc |= (wv >= 0.0f ? 1u : 0u) << bi;
            }
            b[wd] = acc;
        }
        dst[o * 9 + tap] = make_uint4(b[0], b[1], b[2], b[3]);
    } else if (t < 2432) {
        int c = t - 2304;
        float i1 = __fdiv_rn(g1[c], __fsqrt_rn(__fadd_rn(v1[c], 1e-5f)));
        bnc[c]       = i1;
        bnc[128 + c] = __fsub_rn(b1[c], __fmul_rn(m1[c], i1));
        float i2 = __fdiv_rn(g2[c], __fsqrt_rn(__fadd_rn(v2[c], 1e-5f)));
        bnc[256 + c] = i2;
        bnc[384 + c] = __fsub_rn(b2[c], __fmul_rn(m2[c], i2));
    }
}

// Stage 1: 512 threads. Waves 0-3 (grp 0): conv j in [0,64): bits2 even bits,
// idle odd bits, res1, bits2 write. Waves 4-7 (grp 1): conv j in [64,128):
// final[4m+1]; plus pass-through final[4m+3].
__global__ __launch_bounds__(512) void stage1_kernel(
    const float* __restrict__ x, const uint4* __restrict__ w1b,
    const float* __restrict__ bnc, const float* __restrict__ move0,
    const float* __restrict__ move1,
    uint4* __restrict__ bits2, __hip_bfloat16* __restrict__ res1,
    float* __restrict__ out)
{
    const int blk = blockIdx.x;
    const int tile = blk % TILES;
    const int n = blk / TILES;
    const int h0 = tile * TH;
    const int tid = threadIdx.x;

    __shared__ uint32_t sb[(TH + 2) * 60 * 4];   // input bits, row stride 60 uint4
    __shared__ uint4 wl[128 * 9];                // binarized weights (18KB)

    const float* xn = x + (size_t)n * 256 * HW;

    // weights -> LDS
    for (int i = tid; i < 128 * 9; i += 512) wl[i] = w1b[i];

    // binarize x_act (ch 0..127) for tile+halo into LDS
    for (int hp = tid; hp < (TH + 2) * 58; hp += 512) {
        int hr = hp / 58, hc = hp % 58;
        int gh = h0 - 1 + hr, gw = hc - 1;
        uint32_t wds[4] = {0, 0, 0, 0};
        if (gh >= 0 && gh < HH && gw >= 0 && gw < WW) {
            const float* xp = xn + gh * WW + gw;
            #pragma unroll
            for (int wd = 0; wd < 4; ++wd) {
                uint32_t acc = 0;
                #pragma unroll
                for (int bi = 0; bi < 32; ++bi) {
                    float v = xp[(size_t)(wd * 32 + bi) * HW];
                    acc |= (v >= 0.0f ? 1u : 0u) << bi;
                }
                wds[wd] = acc;
            }
        }
        int l = (hr * 60 + hc) * 4;
        sb[l] = wds[0]; sb[l + 1] = wds[1]; sb[l + 2] = wds[2]; sb[l + 3] = wds[3];
    }
    __syncthreads();

    const int grp = tid >> 8;      // 0: j 0..63, 1: j 64..127
    const int lt = tid & 255;

    if (lt < TH * WW) {
        const int r = lt / WW, cl = lt % WW;
        const int gh = h0 + r;
        const uint4* sb4 = (const uint4*)sb;
        const int rok0 = (gh >= 1), rok2 = (gh <= HH - 2);
        const int cok0 = (cl >= 1), cok2 = (cl <= WW - 2);
        const uint32_t rs0 = rok0 ? ~0u : 0u, rs2 = rok2 ? ~0u : 0u;
        const uint32_t csL = cok0 ? ~0u : 0u, csR = cok2 ? ~0u : 0u;
        const int nvbase = ((1 + rok0 + rok2) * (1 + cok0 + cok2)) << 7;
        const uint4 i00 = sb4[(r + 0) * 60 + cl + 0];
        const uint4 i01 = sb4[(r + 0) * 60 + cl + 1];
        const uint4 i02 = sb4[(r + 0) * 60 + cl + 2];
        const uint4 i10 = sb4[(r + 1) * 60 + cl + 0];
        const uint4 i11 = sb4[(r + 1) * 60 + cl + 1];
        const uint4 i12 = sb4[(r + 1) * 60 + cl + 2];
        const uint4 i20 = sb4[(r + 2) * 60 + cl + 0];
        const uint4 i21 = sb4[(r + 2) * 60 + cl + 1];
        const uint4 i22 = sb4[(r + 2) * 60 + cl + 2];

        const int poff = gh * WW + cl;
        const int jbase = grp << 6;
        uint32_t bw0 = 0, bw1 = 0, bw2 = 0, bw3 = 0;

        for (int jj = 0; jj < 64; ++jj) {
            const int j = jbase + jj;
            const uint4* wt = &wl[j * 9];
            int acc = 0;
            acc += PC(wt[0], i00) & (int)(rs0 & csL);
            acc += PC(wt[1], i01) & (int)rs0;
            acc += PC(wt[2], i02) & (int)(rs0 & csR);
            acc += PC(wt[3], i10) & (int)csL;
            acc += PC(wt[4], i11);
            acc += PC(wt[5], i12) & (int)csR;
            acc += PC(wt[6], i20) & (int)(rs2 & csL);
            acc += PC(wt[7], i21) & (int)rs2;
            acc += PC(wt[8], i22) & (int)(rs2 & csR);
            float convf = (float)(nvbase - (acc << 1));
            float bno = __fadd_rn(__fmul_rn(convf, bnc[j]), bnc[128 + j]);
            float resv = xn[(size_t)j * HW + poff];
            float v2 = __fadd_rn(bno, resv);
            float vc = fminf(fmaxf(v2, -1.0f), 1.0f);
            if (grp == 0) {
                // shuffled ch2 = 2j -> bits2 word j>>4, bit 2*(j&15)
                uint32_t m = (v2 >= 0.0f ? 1u : 0u) << (2 * (j & 15));
                int wd = j >> 4;
                if (wd == 0) bw0 |= m; else if (wd == 1) bw1 |= m;
                else if (wd == 2) bw2 |= m; else bw3 |= m;
                res1[(size_t)(n * 64 + j) * HW + poff] = __float2bfloat16(vc);
            } else {
                // final[4m+1] = out1_ht[64+m] + move1[2m], m = j-64
                int i2 = 2 * (j - 64);
                out[(size_t)(n * 256 + 2 * i2 + 1) * HW + poff] =
                    __fadd_rn(vc, move1[i2]);
            }
        }
        if (grp == 0) {
            // idle bits: shuffled ch2 = 2k+1 from sign(x[128+k] + move0[k])
            for (int k2 = 0; k2 < 64; ++k2) {
                float v = xn[(size_t)(128 + k2) * HW + poff];
                float s = __fadd_rn(v, move0[k2]);
                uint32_t m = (s >= 0.0f ? 1u : 0u) << (2 * (k2 & 15) + 1);
                int wd = k2 >> 4;
                if (wd == 0) bw0 |= m; else if (wd == 1) bw1 |= m;
                else if (wd == 2) bw2 |= m; else bw3 |= m;
            }
            bits2[(size_t)n * HW + poff] = make_uint4(bw0, bw1, bw2, bw3);
        }
    }

    // pass-through planes 4m+3 = x[192+m] + move0[64+m] + move1[2m+1]  (grp 1)
    if (grp == 1) {
        for (int idx = lt; idx < 64 * TH * WW; idx += 256) {
            int m = idx / (TH * WW);
            int p = idx % (TH * WW);
            int lh = p / WW, lw = p % WW;
            int poff = (h0 + lh) * WW + lw;
            float xv = xn[(size_t)(192 + m) * HW + poff];
            float val = __fadd_rn(__fadd_rn(xv, move0[64 + m]), move1[2 * m + 1]);
            out[(size_t)(n * 256 + 4 * m + 3) * HW + poff] = val;
        }
    }
}

// Stage 2: 512 threads, conv2 + bn2 + residual + hardtanh -> even planes 2j.
// grp 0: j 0..63; grp 1: j 64..127.
__global__ __launch_bounds__(512) void stage2_kernel(
    const float* __restrict__ x, const uint4* __restrict__ w2b,
    const float* __restrict__ bnc, const float* __restrict__ move0,
    const uint4* __restrict__ bits2, const __hip_bfloat16* __restrict__ res1,
    float* __restrict__ out)
{
    const int blk = blockIdx.x;
    const int tile = blk % TILES;
    const int n = blk / TILES;
    const int h0 = tile * TH;
    const int tid = threadIdx.x;

    __shared__ uint32_t sb[(TH + 2) * 60 * 4];
    __shared__ uint4 wl[128 * 9];

    for (int i = tid; i < 128 * 9; i += 512) wl[i] = w2b[i];

    const uint4* bsrc = bits2 + (size_t)n * HW;
    for (int hp = tid; hp < (TH + 2) * 58; hp += 512) {
        int hr = hp / 58, hc = hp % 58;
        int gh = h0 - 1 + hr, gw = hc - 1;
        uint4 v = make_uint4(0, 0, 0, 0);
        if (gh >= 0 && gh < HH && gw >= 0 && gw < WW) v = bsrc[gh * WW + gw];
        int l = (hr * 60 + hc) * 4;
        sb[l] = v.x; sb[l + 1] = v.y; sb[l + 2] = v.z; sb[l + 3] = v.w;
    }
    __syncthreads();

    const int grp = tid >> 8;
    const int lt = tid & 255;
    if (lt >= TH * WW) return;
    const int r = lt / WW, cl = lt % WW;
    const int gh = h0 + r;
    const uint4* sb4 = (const uint4*)sb;
    const int rok0 = (gh >= 1), rok2 = (gh <= HH - 2);
    const int cok0 = (cl >= 1), cok2 = (cl <= WW - 2);
    const uint32_t rs0 = rok0 ? ~0u : 0u, rs2 = rok2 ? ~0u : 0u;
    const uint32_t csL = cok0 ? ~0u : 0u, csR = cok2 ? ~0u : 0u;
    const int nvbase = ((1 + rok0 + rok2) * (1 + cok0 + cok2)) << 7;
    const uint4 i00 = sb4[(r + 0) * 60 + cl + 0];
    const uint4 i01 = sb4[(r + 0) * 60 + cl + 1];
    const uint4 i02 = sb4[(r + 0) * 60 + cl + 2];
    const uint4 i10 = sb4[(r + 1) * 60 + cl + 0];
    const uint4 i11 = sb4[(r + 1) * 60 + cl + 1];
    const uint4 i12 = sb4[(r + 1) * 60 + cl + 2];
    const uint4 i20 = sb4[(r + 2) * 60 + cl + 0];
    const uint4 i21 = sb4[(r + 2) * 60 + cl + 1];
    const uint4 i22 = sb4[(r + 2) * 60 + cl + 2];

    const float* xn = x + (size_t)n * 256 * HW;
    const int poff = gh * WW + cl;
    const int jbase = grp << 6;

    for (int jj = 0; jj < 64; ++jj) {
        const int j = jbase + jj;
        const uint4* wt = &wl[j * 9];
        int acc = 0;
        acc += PC(wt[0], i00) & (int)(rs0 & csL);
        acc += PC(wt[1], i01) & (int)rs0;
        acc += PC(wt[2], i02) & (int)(rs0 & csR);
        acc += PC(wt[3], i10) & (int)csL;
        acc += PC(wt[4], i11);
        acc += PC(wt[5], i12) & (int)csR;
        acc += PC(wt[6], i20) & (int)(rs2 & csL);
        acc += PC(wt[7], i21) & (int)rs2;
        acc += PC(wt[8], i22) & (int)(rs2 & csR);
        float convf = (float)(nvbase - (acc << 1));
        float bno = __fadd_rn(__fmul_rn(convf, bnc[256 + j]), bnc[384 + j]);
        float resv;
        if (j & 1) {
            resv = __fadd_rn(xn[(size_t)(128 + (j >> 1)) * HW + poff], move0[j >> 1]);
        } else {
            resv = __bfloat162float(res1[(size_t)(n * 64 + (j >> 1)) * HW + poff]);
        }
        float v2 = __fadd_rn(bno, resv);
        float vc = fminf(fmaxf(v2, -1.0f), 1.0f);
        out[(size_t)(n * 256 + 2 * j) * HW + poff] = vc;
    }
}

extern "C" void kernel_launch(void* const* d_in, const int* in_sizes, int n_in,
                              void* d_out, int out_size, void* d_ws, size_t ws_size,
                              hipStream_t stream)
{
    const float* x   = (const float*)d_in[0];
    const float* w1  = (const float*)d_in[1];
    const float* w2  = (const float*)d_in[2];
    const float* g1  = (const float*)d_in[3];
    const float* b1  = (const float*)d_in[4];
    const float* m1  = (const float*)d_in[5];
    const float* v1  = (const float*)d_in[6];
    const float* g2  = (const float*)d_in[7];
    const float* b2  = (const float*)d_in[8];
    const float* m2  = (const float*)d_in[9];
    const float* v2  = (const float*)d_in[10];
    const float* mv0 = (const float*)d_in[11];
    const float* mv1 = (const float*)d_in[12];

    uint8_t* ws = (uint8_t*)d_ws;
    uint4* w1b = (uint4*)(ws + WS_W1B);
    uint4* w2b = (uint4*)(ws + WS_W2B);
    float* bnc = (float*)(ws + WS_BN);
    uint4* bits2 = (uint4*)(ws + WS_BITS2);
    __hip_bfloat16* res1 = (__hip_bfloat16*)(ws + WS_RES1);
    float* outp = (float*)d_out;

    hipLaunchKernelGGL(prep_kernel, dim3(10), dim3(256), 0, stream,
                       w1, w2, g1, b1, m1, v1, g2, b2, m2, v2, w1b, w2b, bnc);
    hipLaunchKernelGGL(stage1_kernel, dim3(TILES * NBATCH), dim3(512), 0, stream,
                       x, w1b, bnc, mv0, mv1, bits2, res1, outp);
    hipLaunchKernelGGL(stage2_kernel, dim3(TILES * NBATCH), dim3(512), 0, stream,
                       x, w2b, bnc, mv0, bits2, res1, outp);
}

// Round 6
// 132.135 us; speedup vs baseline: 1.5133x; 1.2366x over previous
//
#include <hip/hip_runtime.h>
#include <hip/hip_bf16.h>
#include <stdint.h>

// BasicBlock: binarized ShuffleNet-style block via XNOR-popcount conv.
// conv = 128*nv - 2*popcount(bits_in ^ bits_w) over valid taps (exact integers).
// R6: occupancy fix — separate binarize kernel + 4-way out-channel split conv
// kernels (1792 small blocks, 28 waves/CU) + int8 res1 (ws stays < 10MB).

#define HH 56
#define WW 56
#define HW 3136
#define TH 4            // tile rows per conv block
#define TILES 14        // 56/TH
#define NBATCH 32
#define NPX (NBATCH * HW)   // 100352 total pixels

// ws layout (bytes)
#define WS_W1B   0u          // 128*9 uint4 = 18432
#define WS_W2B   18432u      // 18432
#define WS_BN    36864u      // floats inv1[128] c1[128] inv2[128] c2[128] = 2048
#define WS_BITS2 40960u      // uint4 per pixel: 100352*16 = 1605632
#define WS_BITS1 1646592u    // 1605632
#define WS_RES1  3252224u    // int8: 64 planes * 100352 = 6422528 (end 9.7MB)

#define PC(a,b) (__popc((a).x ^ (b).x) + __popc((a).y ^ (b).y) + \
                 __popc((a).z ^ (b).z) + __popc((a).w ^ (b).w))

__global__ __launch_bounds__(256) void prep_kernel(
    const float* __restrict__ w1, const float* __restrict__ w2,
    const float* __restrict__ g1, const float* __restrict__ b1,
    const float* __restrict__ m1, const float* __restrict__ v1,
    const float* __restrict__ g2, const float* __restrict__ b2,
    const float* __restrict__ m2, const float* __restrict__ v2,
    uint4* __restrict__ w1b, uint4* __restrict__ w2b, float* __restrict__ bnc)
{
    int t = blockIdx.x * 256 + threadIdx.x;
    if (t < 2304) {
        const float* w = (t < 1152) ? w1 : w2;
        uint4* dst = (t < 1152) ? w1b : w2b;
        int tt = (t < 1152) ? t : t - 1152;
        int o = tt / 9, tap = tt % 9;
        const float* wp = w + (size_t)o * 1152 + tap;
        uint32_t b[4];
        #pragma unroll
        for (int wd = 0; wd < 4; ++wd) {
            uint32_t acc = 0;
            #pragma unroll
            for (int bi = 0; bi < 32; ++bi) {
                float wv = wp[(size_t)(wd * 32 + bi) * 9];
                acc |= (wv >= 0.0f ? 1u : 0u) << bi;
            }
            b[wd] = acc;
        }
        dst[o * 9 + tap] = make_uint4(b[0], b[1], b[2], b[3]);
    } else if (t < 2432) {
        int c = t - 2304;
        float i1 = __fdiv_rn(g1[c], __fsqrt_rn(__fadd_rn(v1[c], 1e-5f)));
        bnc[c]       = i1;
        bnc[128 + c] = __fsub_rn(b1[c], __fmul_rn(m1[c], i1));
        float i2 = __fdiv_rn(g2[c], __fsqrt_rn(__fadd_rn(v2[c], 1e-5f)));
        bnc[256 + c] = i2;
        bnc[384 + c] = __fsub_rn(b2[c], __fmul_rn(m2[c], i2));
    }
}

// Kernel A: per-pixel packing + pass-through planes. grid = 392*5, 256 thr.
//  g0: bits1 words 0,1 (ch 0..63)     g1: bits1 words 2,3 (ch 64..127)
//  g2: bits2 odd (idle) bits from sign(x[128+k]+move0[k])
//  g3/g4: out planes 4m+3 = x[192+m]+move0[64+m]+move1[2m+1], m split 32/32
__global__ __launch_bounds__(256) void binpack_kernel(
    const float* __restrict__ x, const float* __restrict__ move0,
    const float* __restrict__ move1,
    uint4* __restrict__ bits1, uint4* __restrict__ bits2,
    float* __restrict__ out)
{
    const int g = blockIdx.x / 392;
    const int px = (blockIdx.x % 392) * 256 + threadIdx.x;   // < NPX exactly
    const int n = px / HW, poff = px % HW;
    const float* xn = x + (size_t)n * 256 * HW + poff;

    if (g < 2) {
        const int cb = g * 64;
        uint32_t w0 = 0, w1 = 0;
        #pragma unroll
        for (int c = 0; c < 32; ++c)
            w0 |= (xn[(size_t)(cb + c) * HW] >= 0.0f ? 1u : 0u) << c;
        #pragma unroll
        for (int c = 0; c < 32; ++c)
            w1 |= (xn[(size_t)(cb + 32 + c) * HW] >= 0.0f ? 1u : 0u) << c;
        ((uint2*)&bits1[px])[g] = make_uint2(w0, w1);
    } else if (g == 2) {
        uint32_t w0 = 0, w1 = 0, w2 = 0, w3 = 0;
        #pragma unroll
        for (int k = 0; k < 64; ++k) {
            float s = __fadd_rn(xn[(size_t)(128 + k) * HW], move0[k]);
            uint32_t m = (s >= 0.0f ? 1u : 0u) << (2 * (k & 15) + 1);
            if ((k >> 4) == 0) w0 |= m; else if ((k >> 4) == 1) w1 |= m;
            else if ((k >> 4) == 2) w2 |= m; else w3 |= m;
        }
        bits2[px] = make_uint4(w0, w1, w2, w3);
    } else {
        const int mb = (g - 3) * 32;
        for (int mm = 0; mm < 32; ++mm) {
            int m = mb + mm;
            float v = __fadd_rn(__fadd_rn(xn[(size_t)(192 + m) * HW],
                                          move0[64 + m]), move1[2 * m + 1]);
            out[(size_t)(n * 256 + 4 * m + 3) * HW + poff] = v;
        }
    }
}

// Kernel B: conv1, out-channel split js (j = 32*js + jj).
//  js 0,1: bits2 even bits (words 2js,2js+1, OR with A's odd bits) + res1 int8
//  js 2,3: out planes 4m+1 = hardtanh(...)+move1[2m], m=j-64
__global__ __launch_bounds__(256) void conv1_kernel(
    const float* __restrict__ x, const uint4* __restrict__ w1b,
    const float* __restrict__ bnc, const float* __restrict__ move1,
    const uint4* __restrict__ bits1, uint4* __restrict__ bits2,
    int8_t* __restrict__ res1, float* __restrict__ out)
{
    const int b = blockIdx.x;
    const int js = b & 3;
    const int tile = (b >> 2) % TILES;
    const int n = (b >> 2) / TILES;
    const int h0 = tile * TH;
    const int tid = threadIdx.x;

    __shared__ uint4 sb[(TH + 2) * 60];
    __shared__ uint4 wl[32 * 9];

    const uint4* bsrc = bits1 + (size_t)n * HW;
    for (int hp = tid; hp < (TH + 2) * 58; hp += 256) {
        int hr = hp / 58, hc = hp % 58;
        int gh = h0 - 1 + hr, gw = hc - 1;
        uint4 v = make_uint4(0, 0, 0, 0);
        if (gh >= 0 && gh < HH && gw >= 0 && gw < WW) v = bsrc[gh * WW + gw];
        sb[hr * 60 + hc] = v;
    }
    for (int i = tid; i < 32 * 9; i += 256) wl[i] = w1b[js * 288 + i];
    __syncthreads();

    if (tid >= TH * WW) return;
    const int r = tid / WW, cl = tid % WW;
    const int gh = h0 + r;
    const int rok0 = (gh >= 1), rok2 = (gh <= HH - 2);
    const int cok0 = (cl >= 1), cok2 = (cl <= WW - 2);
    const uint32_t rs0 = rok0 ? ~0u : 0u, rs2 = rok2 ? ~0u : 0u;
    const uint32_t csL = cok0 ? ~0u : 0u, csR = cok2 ? ~0u : 0u;
    const int nvbase = ((1 + rok0 + rok2) * (1 + cok0 + cok2)) << 7;
    const uint4 i00 = sb[(r + 0) * 60 + cl + 0];
    const uint4 i01 = sb[(r + 0) * 60 + cl + 1];
    const uint4 i02 = sb[(r + 0) * 60 + cl + 2];
    const uint4 i10 = sb[(r + 1) * 60 + cl + 0];
    const uint4 i11 = sb[(r + 1) * 60 + cl + 1];
    const uint4 i12 = sb[(r + 1) * 60 + cl + 2];
    const uint4 i20 = sb[(r + 2) * 60 + cl + 0];
    const uint4 i21 = sb[(r + 2) * 60 + cl + 1];
    const uint4 i22 = sb[(r + 2) * 60 + cl + 2];

    const float* xn = x + (size_t)n * 256 * HW;
    const int poff = gh * WW + cl;
    uint32_t bw0 = 0, bw1 = 0;

    for (int jj = 0; jj < 32; ++jj) {
        const int j = js * 32 + jj;
        const uint4* wt = &wl[jj * 9];
        int acc = 0;
        acc += PC(wt[0], i00) & (int)(rs0 & csL);
        acc += PC(wt[1], i01) & (int)rs0;
        acc += PC(wt[2], i02) & (int)(rs0 & csR);
        acc += PC(wt[3], i10) & (int)csL;
        acc += PC(wt[4], i11);
        acc += PC(wt[5], i12) & (int)csR;
        acc += PC(wt[6], i20) & (int)(rs2 & csL);
        acc += PC(wt[7], i21) & (int)rs2;
        acc += PC(wt[8], i22) & (int)(rs2 & csR);
        float convf = (float)(nvbase - (acc << 1));
        float bno = __fadd_rn(__fmul_rn(convf, bnc[j]), bnc[128 + j]);
        float resv = xn[(size_t)j * HW + poff];
        float v2 = __fadd_rn(bno, resv);
        float vc = fminf(fmaxf(v2, -1.0f), 1.0f);
        if (js < 2) {
            uint32_t m = (v2 >= 0.0f ? 1u : 0u) << (2 * (j & 15));
            if (jj & 16) bw1 |= m; else bw0 |= m;
            res1[(size_t)(n * 64 + j) * HW + poff] =
                (int8_t)__float2int_rn(__fmul_rn(vc, 127.0f));
        } else {
            int m = j - 64;
            out[(size_t)(n * 256 + 4 * m + 1) * HW + poff] =
                __fadd_rn(vc, move1[2 * m]);
        }
    }
    if (js < 2) {
        uint2* dst = (uint2*)&bits2[(size_t)n * HW + poff];
        uint2 old = dst[js];                 // odd (idle) bits from kernel A
        dst[js] = make_uint2(old.x | bw0, old.y | bw1);
    }
}

// Kernel C: conv2, out-channel split js. out plane 2j.
__global__ __launch_bounds__(256) void conv2_kernel(
    const float* __restrict__ x, const uint4* __restrict__ w2b,
    const float* __restrict__ bnc, const float* __restrict__ move0,
    const uint4* __restrict__ bits2, const int8_t* __restrict__ res1,
    float* __restrict__ out)
{
    const int b = blockIdx.x;
    const int js = b & 3;
    const int tile = (b >> 2) % TILES;
    const int n = (b >> 2) / TILES;
    const int h0 = tile * TH;
    const int tid = threadIdx.x;

    __shared__ uint4 sb[(TH + 2) * 60];
    __shared__ uint4 wl[32 * 9];

    const uint4* bsrc = bits2 + (size_t)n * HW;
    for (int hp = tid; hp < (TH + 2) * 58; hp += 256) {
        int hr = hp / 58, hc = hp % 58;
        int gh = h0 - 1 + hr, gw = hc - 1;
        uint4 v = make_uint4(0, 0, 0, 0);
        if (gh >= 0 && gh < HH && gw >= 0 && gw < WW) v = bsrc[gh * WW + gw];
        sb[hr * 60 + hc] = v;
    }
    for (int i = tid; i < 32 * 9; i += 256) wl[i] = w2b[js * 288 + i];
    __syncthreads();

    if (tid >= TH * WW) return;
    const int r = tid / WW, cl = tid % WW;
    const int gh = h0 + r;
    const int rok0 = (gh >= 1), rok2 = (gh <= HH - 2);
    const int cok0 = (cl >= 1), cok2 = (cl <= WW - 2);
    const uint32_t rs0 = rok0 ? ~0u : 0u, rs2 = rok2 ? ~0u : 0u;
    const uint32_t csL = cok0 ? ~0u : 0u, csR = cok2 ? ~0u : 0u;
    const int nvbase = ((1 + rok0 + rok2) * (1 + cok0 + cok2)) << 7;
    const uint4 i00 = sb[(r + 0) * 60 + cl + 0];
    const uint4 i01 = sb[(r + 0) * 60 + cl + 1];
    const uint4 i02 = sb[(r + 0) * 60 + cl + 2];
    const uint4 i10 = sb[(r + 1) * 60 + cl + 0];
    const uint4 i11 = sb[(r + 1) * 60 + cl + 1];
    const uint4 i12 = sb[(r + 1) * 60 + cl + 2];
    const uint4 i20 = sb[(r + 2) * 60 + cl + 0];
    const uint4 i21 = sb[(r + 2) * 60 + cl + 1];
    const uint4 i22 = sb[(r + 2) * 60 + cl + 2];

    const float* xn = x + (size_t)n * 256 * HW;
    const int poff = gh * WW + cl;

    for (int jj = 0; jj < 32; ++jj) {
        const int j = js * 32 + jj;
        const uint4* wt = &wl[jj * 9];
        int acc = 0;
        acc += PC(wt[0], i00) & (int)(rs0 & csL);
        acc += PC(wt[1], i01) & (int)rs0;
        acc += PC(wt[2], i02) & (int)(rs0 & csR);
        acc += PC(wt[3], i10) & (int)csL;
        acc += PC(wt[4], i11);
        acc += PC(wt[5], i12) & (int)csR;
        acc += PC(wt[6], i20) & (int)(rs2 & csL);
        acc += PC(wt[7], i21) & (int)rs2;
        acc += PC(wt[8], i22) & (int)(rs2 & csR);
        float convf = (float)(nvbase - (acc << 1));
        float bno = __fadd_rn(__fmul_rn(convf, bnc[256 + j]), bnc[384 + j]);
        float resv;
        if (j & 1) {
            resv = __fadd_rn(xn[(size_t)(128 + (j >> 1)) * HW + poff],
                             move0[j >> 1]);
        } else {
            int q = res1[(size_t)(n * 64 + (j >> 1)) * HW + poff];
            resv = __fmul_rn(__int2float_rn(q), 1.0f / 127.0f);
        }
        float v2 = __fadd_rn(bno, resv);
        float vc = fminf(fmaxf(v2, -1.0f), 1.0f);
        out[(size_t)(n * 256 + 2 * j) * HW + poff] = vc;
    }
}

extern "C" void kernel_launch(void* const* d_in, const int* in_sizes, int n_in,
                              void* d_out, int out_size, void* d_ws, size_t ws_size,
                              hipStream_t stream)
{
    const float* x   = (const float*)d_in[0];
    const float* w1  = (const float*)d_in[1];
    const float* w2  = (const float*)d_in[2];
    const float* g1  = (const float*)d_in[3];
    const float* b1  = (const float*)d_in[4];
    const float* m1  = (const float*)d_in[5];
    const float* v1  = (const float*)d_in[6];
    const float* g2  = (const float*)d_in[7];
    const float* b2  = (const float*)d_in[8];
    const float* m2  = (const float*)d_in[9];
    const float* v2  = (const float*)d_in[10];
    const float* mv0 = (const float*)d_in[11];
    const float* mv1 = (const float*)d_in[12];

    uint8_t* ws = (uint8_t*)d_ws;
    uint4* w1b = (uint4*)(ws + WS_W1B);
    uint4* w2b = (uint4*)(ws + WS_W2B);
    float* bnc = (float*)(ws + WS_BN);
    uint4* bits2 = (uint4*)(ws + WS_BITS2);
    uint4* bits1 = (uint4*)(ws + WS_BITS1);
    int8_t* res1 = (int8_t*)(ws + WS_RES1);
    float* outp = (float*)d_out;

    hipLaunchKernelGGL(prep_kernel, dim3(10), dim3(256), 0, stream,
                       w1, w2, g1, b1, m1, v1, g2, b2, m2, v2, w1b, w2b, bnc);
    hipLaunchKernelGGL(binpack_kernel, dim3(392 * 5), dim3(256), 0, stream,
                       x, mv0, mv1, bits1, bits2, outp);
    hipLaunchKernelGGL(conv1_kernel, dim3(TILES * NBATCH * 4), dim3(256), 0, stream,
                       x, w1b, bnc, mv1, bits1, bits2, res1, outp);
    hipLaunchKernelGGL(conv2_kernel, dim3(TILES * NBATCH * 4), dim3(256), 0, stream,
                       x, w2b, bnc, mv0, bits2, res1, outp);
}

// Round 7
// 118.300 us; speedup vs baseline: 1.6903x; 1.1170x over previous
//
#include <hip/hip_runtime.h>
#include <stdint.h>

// BasicBlock: binarized ShuffleNet-style block via XNOR-popcount conv.
// conv = 128*nv - 2*popcount(bits_in ^ bits_w) over valid taps (exact integers).
// R7: 448-thread strip blocks (8 rows, 100% lane use), js=8 channel split
// (1792 blocks x 7 waves -> 28 waves/CU), px-major uint2 res1, dword bits2 RMW.

#define HH 56
#define WW 56
#define HW 3136
#define NBATCH 32
#define NPX (NBATCH * HW)   // 100352

// ws layout (bytes)
#define WS_W1B   0u          // 128*9 uint4 = 18432
#define WS_W2B   18432u      // 18432
#define WS_BN    36864u      // floats inv1[128] c1[128] inv2[128] c2[128]
#define WS_BITS2 40960u      // uint4 per pixel: 100352*16 = 1605632
#define WS_BITS1 1646592u    // 1605632
#define WS_RES1  3252224u    // int8 [8 groups][NPX][8B] = 6422528 (end 9.7MB)

#define PC(a,b) (__popc((a).x ^ (b).x) + __popc((a).y ^ (b).y) + \
                 __popc((a).z ^ (b).z) + __popc((a).w ^ (b).w))

__global__ __launch_bounds__(256) void prep_kernel(
    const float* __restrict__ w1, const float* __restrict__ w2,
    const float* __restrict__ g1, const float* __restrict__ b1,
    const float* __restrict__ m1, const float* __restrict__ v1,
    const float* __restrict__ g2, const float* __restrict__ b2,
    const float* __restrict__ m2, const float* __restrict__ v2,
    uint4* __restrict__ w1b, uint4* __restrict__ w2b, float* __restrict__ bnc)
{
    int t = blockIdx.x * 256 + threadIdx.x;
    if (t < 2304) {
        const float* w = (t < 1152) ? w1 : w2;
        uint4* dst = (t < 1152) ? w1b : w2b;
        int tt = (t < 1152) ? t : t - 1152;
        int o = tt / 9, tap = tt % 9;
        const float* wp = w + (size_t)o * 1152 + tap;
        uint32_t b[4];
        #pragma unroll
        for (int wd = 0; wd < 4; ++wd) {
            uint32_t acc = 0;
            #pragma unroll
            for (int bi = 0; bi < 32; ++bi) {
                float wv = wp[(size_t)(wd * 32 + bi) * 9];
                acc |= (wv >= 0.0f ? 1u : 0u) << bi;
            }
            b[wd] = acc;
        }
        dst[o * 9 + tap] = make_uint4(b[0], b[1], b[2], b[3]);
    } else if (t < 2432) {
        int c = t - 2304;
        float i1 = __fdiv_rn(g1[c], __fsqrt_rn(__fadd_rn(v1[c], 1e-5f)));
        bnc[c]       = i1;
        bnc[128 + c] = __fsub_rn(b1[c], __fmul_rn(m1[c], i1));
        float i2 = __fdiv_rn(g2[c], __fsqrt_rn(__fadd_rn(v2[c], 1e-5f)));
        bnc[256 + c] = i2;
        bnc[384 + c] = __fsub_rn(b2[c], __fmul_rn(m2[c], i2));
    }
}

// Kernel A: per-pixel packing + pass-through planes. grid = 392*5, 256 thr.
//  g0: bits1 words 0,1 (ch 0..63)     g1: bits1 words 2,3 (ch 64..127)
//  g2: bits2 odd (idle) bits from sign(x[128+k]+move0[k]) (even bits = 0)
//  g3/g4: out planes 4m+3 = x[192+m]+move0[64+m]+move1[2m+1], m split 32/32
__global__ __launch_bounds__(256) void binpack_kernel(
    const float* __restrict__ x, const float* __restrict__ move0,
    const float* __restrict__ move1,
    uint4* __restrict__ bits1, uint4* __restrict__ bits2,
    float* __restrict__ out)
{
    const int g = blockIdx.x / 392;
    const int px = (blockIdx.x % 392) * 256 + threadIdx.x;   // < NPX exactly
    const int n = px / HW, poff = px % HW;
    const float* xn = x + (size_t)n * 256 * HW + poff;

    if (g < 2) {
        const int cb = g * 64;
        uint32_t w0 = 0, w1 = 0;
        #pragma unroll
        for (int c = 0; c < 32; ++c)
            w0 |= (xn[(size_t)(cb + c) * HW] >= 0.0f ? 1u : 0u) << c;
        #pragma unroll
        for (int c = 0; c < 32; ++c)
            w1 |= (xn[(size_t)(cb + 32 + c) * HW] >= 0.0f ? 1u : 0u) << c;
        ((uint2*)&bits1[px])[g] = make_uint2(w0, w1);
    } else if (g == 2) {
        uint32_t w0 = 0, w1 = 0, w2 = 0, w3 = 0;
        #pragma unroll
        for (int k = 0; k < 64; ++k) {
            float s = __fadd_rn(xn[(size_t)(128 + k) * HW], move0[k]);
            uint32_t m = (s >= 0.0f ? 1u : 0u) << (2 * (k & 15) + 1);
            if ((k >> 4) == 0) w0 |= m; else if ((k >> 4) == 1) w1 |= m;
            else if ((k >> 4) == 2) w2 |= m; else w3 |= m;
        }
        bits2[px] = make_uint4(w0, w1, w2, w3);
    } else {
        const int mb = (g - 3) * 32;
        for (int mm = 0; mm < 32; ++mm) {
            int m = mb + mm;
            float v = __fadd_rn(__fadd_rn(xn[(size_t)(192 + m) * HW],
                                          move0[64 + m]), move1[2 * m + 1]);
            out[(size_t)(n * 256 + 4 * m + 3) * HW + poff] = v;
        }
    }
}

// Conv kernels: 448 threads, strip of 8 rows (448 px) within one image.
// blockIdx: js = b & 7 (j = 16js + jj), s = b>>3: n = s/7, si = s%7.
// LDS: sb[562] bit-words covering pixels [448si-57, 448si+505); window reads
// are sb[tid + {0,1,2, 56,57,58, 112,113,114}].

// Kernel B: conv1. js<4 (j<64): bits2 even bits (dword js RMW) + res1 uint2x2.
// js>=4: out planes 4m+1 = hardtanh+move1[2m], m = j-64.
__global__ __launch_bounds__(448) void conv1_kernel(
    const float* __restrict__ x, const uint4* __restrict__ w1b,
    const float* __restrict__ bnc, const float* __restrict__ move1,
    const uint4* __restrict__ bits1, uint4* __restrict__ bits2,
    uint2* __restrict__ res1, float* __restrict__ out)
{
    const int b = blockIdx.x;
    const int js = b & 7;
    const int s = b >> 3;
    const int n = s / 7, si = s % 7;
    const int tid = threadIdx.x;

    __shared__ uint4 sb[562];
    __shared__ uint4 wl[144];

    const uint4* bsrc = bits1 + (size_t)n * HW;
    const int base = 448 * si - 57;
    for (int i = tid; i < 562; i += 448) {
        int g = base + i;
        g = (g < 0) ? 0 : ((g > HW - 1) ? HW - 1 : g);
        sb[i] = bsrc[g];
    }
    for (int i = tid; i < 144; i += 448) wl[i] = w1b[js * 144 + i];
    __syncthreads();

    const int poff = 448 * si + tid;
    const int row = poff / WW, col = poff % WW;
    const int rok0 = (row >= 1), rok2 = (row <= HH - 2);
    const int cok0 = (col >= 1), cok2 = (col <= WW - 2);
    const uint32_t rs0 = rok0 ? ~0u : 0u, rs2 = rok2 ? ~0u : 0u;
    const uint32_t csL = cok0 ? ~0u : 0u, csR = cok2 ? ~0u : 0u;
    const int nvbase = ((1 + rok0 + rok2) * (1 + cok0 + cok2)) << 7;
    const uint4 i00 = sb[tid];       const uint4 i01 = sb[tid + 1];
    const uint4 i02 = sb[tid + 2];   const uint4 i10 = sb[tid + 56];
    const uint4 i11 = sb[tid + 57];  const uint4 i12 = sb[tid + 58];
    const uint4 i20 = sb[tid + 112]; const uint4 i21 = sb[tid + 113];
    const uint4 i22 = sb[tid + 114];

    const float* xn = x + (size_t)n * 256 * HW;
    uint32_t bw = 0;
    uint32_t q0 = 0, q1 = 0, q2 = 0, q3 = 0;   // 16 int8 res1 bytes

    #pragma unroll
    for (int jj = 0; jj < 16; ++jj) {
        const int j = js * 16 + jj;
        const uint4* wt = &wl[jj * 9];
        int acc = 0;
        acc += PC(wt[0], i00) & (int)(rs0 & csL);
        acc += PC(wt[1], i01) & (int)rs0;
        acc += PC(wt[2], i02) & (int)(rs0 & csR);
        acc += PC(wt[3], i10) & (int)csL;
        acc += PC(wt[4], i11);
        acc += PC(wt[5], i12) & (int)csR;
        acc += PC(wt[6], i20) & (int)(rs2 & csL);
        acc += PC(wt[7], i21) & (int)rs2;
        acc += PC(wt[8], i22) & (int)(rs2 & csR);
        float convf = (float)(nvbase - (acc << 1));
        float bno = __fadd_rn(__fmul_rn(convf, bnc[j]), bnc[128 + j]);
        float resv = xn[(size_t)j * HW + poff];
        float v2 = __fadd_rn(bno, resv);
        float vc = fminf(fmaxf(v2, -1.0f), 1.0f);
        if (js < 4) {
            bw |= (v2 >= 0.0f ? 1u : 0u) << (2 * jj);
            uint32_t q = (uint32_t)(uint8_t)(int8_t)__float2int_rn(
                __fmul_rn(vc, 127.0f));
            uint32_t sh = 8 * (jj & 3);
            if (jj < 4)       q0 |= q << sh;
            else if (jj < 8)  q1 |= q << sh;
            else if (jj < 12) q2 |= q << sh;
            else              q3 |= q << sh;
        } else {
            int m = j - 64;
            out[(size_t)(n * 256 + 4 * m + 1) * HW + poff] =
                __fadd_rn(vc, move1[2 * m]);
        }
    }
    if (js < 4) {
        const size_t px = (size_t)n * HW + poff;
        // res1 layout: [js2 group][px] uint2 (8 int8). conv1 js covers
        // js2 = 2js (bytes jj 0..7) and 2js+1 (jj 8..15).
        res1[(size_t)(2 * js) * NPX + px]     = make_uint2(q0, q1);
        res1[(size_t)(2 * js + 1) * NPX + px] = make_uint2(q2, q3);
        uint32_t* dst = (uint32_t*)(bits2 + px);
        dst[js] = dst[js] | bw;    // merge with binpack's odd (idle) bits
    }
}

// Kernel C: conv2. j2 = 16js + jj; out plane 2*j2.
// residual: even j2 -> res1 byte (j2>>1) = group js, byte jj>>1;
//           odd  j2 -> x[128 + (j2>>1)] + move0[j2>>1].
__global__ __launch_bounds__(448) void conv2_kernel(
    const float* __restrict__ x, const uint4* __restrict__ w2b,
    const float* __restrict__ bnc, const float* __restrict__ move0,
    const uint4* __restrict__ bits2, const uint2* __restrict__ res1,
    float* __restrict__ out)
{
    const int b = blockIdx.x;
    const int js = b & 7;
    const int s = b >> 3;
    const int n = s / 7, si = s % 7;
    const int tid = threadIdx.x;

    __shared__ uint4 sb[562];
    __shared__ uint4 wl[144];

    const uint4* bsrc = bits2 + (size_t)n * HW;
    const int base = 448 * si - 57;
    for (int i = tid; i < 562; i += 448) {
        int g = base + i;
        g = (g < 0) ? 0 : ((g > HW - 1) ? HW - 1 : g);
        sb[i] = bsrc[g];
    }
    for (int i = tid; i < 144; i += 448) wl[i] = w2b[js * 144 + i];
    __syncthreads();

    const int poff = 448 * si + tid;
    const int row = poff / WW, col = poff % WW;
    const int rok0 = (row >= 1), rok2 = (row <= HH - 2);
    const int cok0 = (col >= 1), cok2 = (col <= WW - 2);
    const uint32_t rs0 = rok0 ? ~0u : 0u, rs2 = rok2 ? ~0u : 0u;
    const uint32_t csL = cok0 ? ~0u : 0u, csR = cok2 ? ~0u : 0u;
    const int nvbase = ((1 + rok0 + rok2) * (1 + cok0 + cok2)) << 7;
    const uint4 i00 = sb[tid];       const uint4 i01 = sb[tid + 1];
    const uint4 i02 = sb[tid + 2];   const uint4 i10 = sb[tid + 56];
    const uint4 i11 = sb[tid + 57];  const uint4 i12 = sb[tid + 58];
    const uint4 i20 = sb[tid + 112]; const uint4 i21 = sb[tid + 113];
    const uint4 i22 = sb[tid + 114];

    const float* xn = x + (size_t)n * 256 * HW;
    const size_t px = (size_t)n * HW + poff;
    const uint2 rq = res1[(size_t)js * NPX + px];   // 8 int8: j1 in [8js,8js+8)

    #pragma unroll
    for (int jj = 0; jj < 16; ++jj) {
        const int j = js * 16 + jj;
        const uint4* wt = &wl[jj * 9];
        int acc = 0;
        acc += PC(wt[0], i00) & (int)(rs0 & csL);
        acc += PC(wt[1], i01) & (int)rs0;
        acc += PC(wt[2], i02) & (int)(rs0 & csR);
        acc += PC(wt[3], i10) & (int)csL;
        acc += PC(wt[4], i11);
        acc += PC(wt[5], i12) & (int)csR;
        acc += PC(wt[6], i20) & (int)(rs2 & csL);
        acc += PC(wt[7], i21) & (int)rs2;
        acc += PC(wt[8], i22) & (int)(rs2 & csR);
        float convf = (float)(nvbase - (acc << 1));
        float bno = __fadd_rn(__fmul_rn(convf, bnc[256 + j]), bnc[384 + j]);
        float resv;
        if (j & 1) {
            resv = __fadd_rn(xn[(size_t)(128 + (j >> 1)) * HW + poff],
                             move0[j >> 1]);
        } else {
            int bidx = jj >> 1;                      // 0..7 within group
            uint32_t wq = (bidx < 4) ? rq.x : rq.y;
            int8_t q = (int8_t)(uint8_t)(wq >> (8 * (bidx & 3)));
            resv = __fmul_rn(__int2float_rn((int)q), 1.0f / 127.0f);
        }
        float v2 = __fadd_rn(bno, resv);
        float vc = fminf(fmaxf(v2, -1.0f), 1.0f);
        out[(size_t)(n * 256 + 2 * j) * HW + poff] = vc;
    }
}

extern "C" void kernel_launch(void* const* d_in, const int* in_sizes, int n_in,
                              void* d_out, int out_size, void* d_ws, size_t ws_size,
                              hipStream_t stream)
{
    const float* x   = (const float*)d_in[0];
    const float* w1  = (const float*)d_in[1];
    const float* w2  = (const float*)d_in[2];
    const float* g1  = (const float*)d_in[3];
    const float* b1  = (const float*)d_in[4];
    const float* m1  = (const float*)d_in[5];
    const float* v1  = (const float*)d_in[6];
    const float* g2  = (const float*)d_in[7];
    const float* b2  = (const float*)d_in[8];
    const float* m2  = (const float*)d_in[9];
    const float* v2  = (const float*)d_in[10];
    const float* mv0 = (const float*)d_in[11];
    const float* mv1 = (const float*)d_in[12];

    uint8_t* ws = (uint8_t*)d_ws;
    uint4* w1b = (uint4*)(ws + WS_W1B);
    uint4* w2b = (uint4*)(ws + WS_W2B);
    float* bnc = (float*)(ws + WS_BN);
    uint4* bits2 = (uint4*)(ws + WS_BITS2);
    uint4* bits1 = (uint4*)(ws + WS_BITS1);
    uint2* res1 = (uint2*)(ws + WS_RES1);
    float* outp = (float*)d_out;

    hipLaunchKernelGGL(prep_kernel, dim3(10), dim3(256), 0, stream,
                       w1, w2, g1, b1, m1, v1, g2, b2, m2, v2, w1b, w2b, bnc);
    hipLaunchKernelGGL(binpack_kernel, dim3(392 * 5), dim3(256), 0, stream,
                       x, mv0, mv1, bits1, bits2, outp);
    hipLaunchKernelGGL(conv1_kernel, dim3(224 * 8), dim3(448), 0, stream,
                       x, w1b, bnc, mv1, bits1, bits2, res1, outp);
    hipLaunchKernelGGL(conv2_kernel, dim3(224 * 8), dim3(448), 0, stream,
                       x, w2b, bnc, mv0, bits2, res1, outp);
}